// Round 9
// baseline (246.808 us; speedup 1.0000x reference)
//
#include <hip/hip_runtime.h>
#include <hip/hip_bf16.h>

#define N_CL   50000
#define FEAT   64
#define HID    256
#define KD     256
#define T_SEL  1000
#define NBLK   782                 // ceil(50000/64) clause groups
#define JSPLIT 4                   // hidden-quarter blocks per clause group (R4-proven)

// ---- bitpack geometry ----
#define WCH    196                 // wave-chunks per row (196*256 = 50176 >= 50000)
#define BPR    784                 // 64-bit words per packed row (WCH*4)
#define CW     56                  // words per clause chunk
#define NCH    14                  // chunks (14*56 = 784)
#define EPB    8                   // events per block
#define GEB    63                  // groups per parity (63*8 = 504 >= 500)

// ---- fallback (R7) geometry ----
#define NQUAD  12500
#define NCHUNK 20
#define CHUNKQ 625
#define GEV    5
#define SLOTS  10
#define LASTW  49

// ws layout (floats). Overlays on P (dead after logits_fin).
#define WK_OFF   0
#define CK_OFF   512
#define MQ_OFF   514
#define P_OFF    520                         // 400000 floats
#define LG_OFF   (P_OFF + JSPLIT * 2 * N_CL) // 400520, 100000 floats
// new path overlays:
#define PTAB_OFF 520                         // uint[2][BPR*64] = 100352 f -> ends 100872
#define ACCB_OFF 100880                      // float4[T_SEL][NCH] = 56000 f -> ends 156880
#define PB_OFF   (LG_OFF + 2 * N_CL)         // 500520: u64[T_SEL][BPR] = 1568000 f
#define GB_OFF   (PB_OFF + 2 * T_SEL * BPR)  // 2068520: same size
#define WS_NEED  ((size_t)(GB_OFF + 2 * T_SEL * BPR) * 4)   // 14,546,080 B
// fallback overlays:
#define CTAB_OFF 520                         // uint4[2][NQUAD] = 100000 f
#define ACCO_OFF (CTAB_OFF + 100000)         // float4[T_SEL][NCHUNK] = 80000 f

__device__ __forceinline__ unsigned fkey(float f) {
    unsigned u = __float_as_uint(f);
    return (u & 0x80000000u) ? ~u : (u | 0x80000000u);
}
__device__ __forceinline__ float finv(unsigned k) {
    unsigned u = (k & 0x80000000u) ? (k ^ 0x80000000u) : ~k;
    return __uint_as_float(u);
}
__device__ __forceinline__ unsigned short f2bf(float f) {   // RNE bf16 pack
    unsigned u = __float_as_uint(f);
    return (unsigned short)((u + 0x7FFFu + ((u >> 16) & 1u)) >> 16);
}
__device__ __forceinline__ float eLO(unsigned u) { return __uint_as_float(u << 16); }
__device__ __forceinline__ float lHI(unsigned u) { return __uint_as_float(u & 0xFFFF0000u); }

// ---------------------------------------------------------------- kernel A
__global__ __launch_bounds__(256) void prep_kernel(
        const float* __restrict__ W2, const float* __restrict__ b2,
        const float* __restrict__ keysW,
        float* __restrict__ wk, float* __restrict__ ck,
        unsigned* __restrict__ mq) {
    __shared__ float sk0[KD], sk1[KD], sb2[KD], red[256];
    int tid = threadIdx.x;
    sk0[tid] = keysW[tid];
    sk1[tid] = keysW[KD + tid];
    sb2[tid] = b2[tid];
    if (tid < 2) mq[tid] = 0u;
    __syncthreads();

    const float* w2r = W2 + (size_t)tid * KD;
    float a0 = 0.f, a1 = 0.f;
    #pragma unroll 4
    for (int k = 0; k < KD; k++) {
        float w = w2r[k];
        a0 = fmaf(w, sk0[k], a0);
        a1 = fmaf(w, sk1[k], a1);
    }
    wk[tid * 2 + 0] = a0;
    wk[tid * 2 + 1] = a1;

    red[tid] = sk0[tid] * sb2[tid];
    __syncthreads();
    for (int s = 128; s > 0; s >>= 1) { if (tid < s) red[tid] += red[tid + s]; __syncthreads(); }
    if (tid == 0) ck[0] = red[0];
    __syncthreads();
    red[tid] = sk1[tid] * sb2[tid];
    __syncthreads();
    for (int s = 128; s > 0; s >>= 1) { if (tid < s) red[tid] += red[tid + s]; __syncthreads(); }
    if (tid == 0) ck[1] = red[0];
}

// ---------------------------------------------------------------- kernel B
// MLP partial logits (R4-proven). k-loop FULLY unrolled -> x[] in VGPRs.
__global__ __launch_bounds__(64, 2) void mlp_kernel(
        const float* __restrict__ X, const float* __restrict__ W1,
        const float* __restrict__ b1, const float* __restrict__ wk,
        float* __restrict__ P) {
    int nb = blockIdx.x >> 2;
    int p  = blockIdx.x & 3;
    int n  = nb * 64 + threadIdx.x;
    int nc = (n < N_CL) ? n : (N_CL - 1);

    float x[FEAT];
    const float4* xp = (const float4*)(X + (size_t)nc * FEAT);
    #pragma unroll
    for (int k4 = 0; k4 < FEAT / 4; k4++) {
        float4 v = xp[k4];
        x[4 * k4 + 0] = v.x; x[4 * k4 + 1] = v.y;
        x[4 * k4 + 2] = v.z; x[4 * k4 + 3] = v.w;
    }

    float l0 = 0.f, l1 = 0.f;
    int j0 = p * 64;
    for (int jg = 0; jg < 64; jg += 16) {
        float h[16];
        #pragma unroll
        for (int u = 0; u < 16; u++) h[u] = b1[j0 + jg + u];
        #pragma unroll
        for (int k = 0; k < FEAT; k++) {
            const float* w1r = W1 + (size_t)k * HID + j0 + jg;
            float xv = x[k];
            #pragma unroll
            for (int u = 0; u < 16; u++) h[u] = fmaf(xv, w1r[u], h[u]);
        }
        #pragma unroll
        for (int u = 0; u < 16; u++) {
            float hv = fmaxf(h[u], 0.0f);
            l0 = fmaf(hv, wk[(j0 + jg + u) * 2 + 0], l0);
            l1 = fmaf(hv, wk[(j0 + jg + u) * 2 + 1], l1);
        }
    }
    if (n < N_CL) {
        P[((size_t)p * 2 + 0) * N_CL + n] = l0;
        P[((size_t)p * 2 + 1) * N_CL + n] = l1;
    }
}

// ---------------------------------------------------------------- kernel C
__global__ __launch_bounds__(256) void logits_fin(
        const float* __restrict__ P, const float* __restrict__ ck,
        float* __restrict__ lg, unsigned* __restrict__ mq) {
    int n = blockIdx.x * 256 + threadIdx.x;
    float m0 = -1e30f, m1 = -1e30f;
    if (n < N_CL) {
        float l0 = ck[0], l1 = ck[1];
        #pragma unroll
        for (int p = 0; p < JSPLIT; p++) {
            l0 += P[((size_t)p * 2 + 0) * N_CL + n];
            l1 += P[((size_t)p * 2 + 1) * N_CL + n];
        }
        lg[n]        = l0;
        lg[N_CL + n] = l1;
        m0 = l0; m1 = l1;
    }
    for (int off = 32; off; off >>= 1) {
        m0 = fmaxf(m0, __shfl_xor(m0, off));
        m1 = fmaxf(m1, __shfl_xor(m1, off));
    }
    __shared__ float sm0[4], sm1[4];
    int w = threadIdx.x >> 6;
    if ((threadIdx.x & 63) == 0) { sm0[w] = m0; sm1[w] = m1; }
    __syncthreads();
    if (threadIdx.x == 0) {
        m0 = fmaxf(fmaxf(sm0[0], sm0[1]), fmaxf(sm0[2], sm0[3]));
        m1 = fmaxf(fmaxf(sm1[0], sm1[1]), fmaxf(sm1[2], sm1[3]));
        atomicMax(mq + 0, fkey(m0));
        atomicMax(mq + 1, fkey(m1));
    }
}

// ================================================================ NEW PATH
// ---------------------------------------------------------------- pack
// Pure stream: one wave per (event, wave-chunk). Read pass+good int4,
// ballot each component -> 8 uint64 words. Clause (wc*256+l*4+j) ->
// word (wc*4+j), bit l. Nothing else: this should run at copy BW.
__global__ __launch_bounds__(256) void pack_kernel(
        const int* __restrict__ pass, const int* __restrict__ good,
        unsigned long long* __restrict__ pb, unsigned long long* __restrict__ gb) {
    int item = blockIdx.x * 4 + (threadIdx.x >> 6);
    int lane = threadIdx.x & 63;
    int t  = item / WCH;
    int wc = item - t * WCH;
    if (t >= T_SEL) return;
    int base = wc * 256 + lane * 4;
    int4 pv = make_int4(0, 0, 0, 0), gv = make_int4(0, 0, 0, 0);
    if (base + 3 < N_CL) {
        pv = *(const int4*)(pass + (size_t)t * N_CL + base);
        gv = *(const int4*)(good + (size_t)t * N_CL + base);
    }
    unsigned long long p0 = __ballot(pv.x), p1 = __ballot(pv.y);
    unsigned long long p2 = __ballot(pv.z), p3 = __ballot(pv.w);
    unsigned long long g0 = __ballot(gv.x), g1 = __ballot(gv.y);
    unsigned long long g2 = __ballot(gv.z), g3 = __ballot(gv.w);
    size_t o = (size_t)t * BPR + wc * 4;
    if (lane == 0) { pb[o] = p0; pb[o + 1] = p1; pb[o + 2] = p2; pb[o + 3] = p3; }
    else if (lane == 1) { gb[o] = g0; gb[o + 1] = g1; gb[o + 2] = g2; gb[o + 3] = g3; }
}

// ---------------------------------------------------------------- eperm
// Value table permuted to ballot bit order: ptab[q][w*64+l] packs
// (bf16(l) << 16) | bf16(exp(l-M)) for clause (w>>2)*256 + l*4 + (w&3).
__global__ __launch_bounds__(256) void eperm_kernel(
        const float* __restrict__ lg, const unsigned* __restrict__ mq,
        unsigned* __restrict__ ptab) {
    int i = blockIdx.x * 256 + threadIdx.x;
    if (i >= 2 * BPR * 64) return;
    int q = i / (BPR * 64);
    int r = i - q * (BPR * 64);
    int w = r >> 6, l = r & 63;
    int clause = ((w >> 2) << 8) + l * 4 + (w & 3);
    unsigned val = 0u;
    if (clause < N_CL) {
        float f = lg[q * N_CL + clause];
        float M = finv(mq[q]);
        val = ((unsigned)f2bf(f) << 16) | (unsigned)f2bf(__expf(f - M));
    }
    ptab[i] = val;
}

// ---------------------------------------------------------------- ebit
// Block = (chunk c of 56 words, parity, 8 events). 14KB value slice in LDS;
// per event read 112 uniform uint64 words; np/ng via __popcll (uniform);
// s/sg via per-lane bit test + LDS value; cross-wave LDS reduce.
__global__ __launch_bounds__(256) void ebit_kernel(
        const unsigned long long* __restrict__ pb,
        const unsigned long long* __restrict__ gb,
        const int* __restrict__ qidx, const unsigned* __restrict__ ptab,
        float4* __restrict__ acc) {
    int bid  = blockIdx.x;
    int c    = bid % NCH;
    int rest = bid / NCH;
    int par  = rest & 1;
    int g    = rest >> 1;
    int tid  = threadIdx.x, wid = tid >> 6, lane = tid & 63;
    int q    = qidx[par] & 1;

    __shared__ unsigned pt[CW * 64];   // 14 KB
    __shared__ float4 red[4];
    {
        const uint4* src = (const uint4*)(ptab + (size_t)q * (BPR * 64) + c * (CW * 64));
        for (int i = tid; i < CW * 64 / 4; i += 256)
            ((uint4*)pt)[i] = src[i];
    }
    __syncthreads();

    for (int e = 0; e < EPB; e++) {
        int ev = g * EPB + e;
        if (ev >= T_SEL / 2) break;
        int t = par + 2 * ev;
        const unsigned long long* pw = pb + (size_t)t * BPR + c * CW + wid * 14;
        const unsigned long long* gw = gb + (size_t)t * BPR + c * CW + wid * 14;

        float sa = 0.f, sga = 0.f;
        int np = 0, ng = 0;
        #pragma unroll
        for (int k = 0; k < 14; k++) {
            unsigned long long wv = pw[k];
            np += (int)__popcll(wv);
            unsigned v = pt[(wid * 14 + k) * 64 + lane];
            if ((wv >> lane) & 1ull) sa += eLO(v);
        }
        #pragma unroll
        for (int k = 0; k < 14; k++) {
            unsigned long long wv = gw[k];
            ng += (int)__popcll(wv);
            unsigned v = pt[(wid * 14 + k) * 64 + lane];
            if ((wv >> lane) & 1ull) sga += lHI(v);
        }
        for (int off = 32; off; off >>= 1) {
            sa  += __shfl_xor(sa, off);
            sga += __shfl_xor(sga, off);
        }
        if (lane == 0) red[wid] = make_float4(sa, sga, (float)np, (float)ng);
        __syncthreads();
        if (tid == 0) {
            float4 a = red[0], b = red[1], cc = red[2], d = red[3];
            acc[(size_t)t * NCH + c] = make_float4(
                a.x + b.x + cc.x + d.x, a.y + b.y + cc.y + d.y,
                a.z + b.z + cc.z + d.z, a.w + b.w + cc.w + d.w);
        }
        __syncthreads();
    }
}

// ---------------------------------------------------------------- final2
__global__ __launch_bounds__(1024) void final2_kernel(
        const int* __restrict__ qidx, const float4* __restrict__ acc,
        const unsigned* __restrict__ mq, float* __restrict__ out) {
    int t = threadIdx.x;
    float s = 0.f, sg = 0.f, np = 0.f, ng = 0.f;
    int q = 0;
    if (t < T_SEL) {
        #pragma unroll 7
        for (int c = 0; c < NCH; c++) {
            float4 a = acc[(size_t)t * NCH + c];
            s += a.x; sg += a.y; np += a.z; ng += a.w;
        }
        q = qidx[t] & 1;
    }
    float M  = finv(mq[q]);
    float nb = np - ng;
    int valid = (t < T_SEL) && (ng > 0.5f) && (nb > 0.5f);

    __shared__ int sc[1024];
    sc[t] = valid;
    __syncthreads();
    for (int off = 1; off < 1024; off <<= 1) {
        int v = (t >= off) ? sc[t - off] : 0;
        __syncthreads();
        sc[t] += v;
        __syncthreads();
    }
    int sb    = sc[t] - valid;
    int steps = sc[1023];

    float ce   = logf(s) + M - sg / fmaxf(ng, 1.0f);
    float wgt  = powf(0.995f, (float)sb) * nb / fmaxf(np, 1.0f);
    float term = valid ? wgt * ce : 0.0f;

    __shared__ float sf[1024];
    sf[t] = term;
    __syncthreads();
    for (int off = 512; off; off >>= 1) {
        if (t < off) sf[t] += sf[t + off];
        __syncthreads();
    }
    if (t == 0) out[0] = sf[0] / fmaxf((float)steps, 1.0f);
}

// ================================================================ FALLBACK (R7, proven)
__global__ __launch_bounds__(256) void epack_kernel(
        const float* __restrict__ lg, const unsigned* __restrict__ mq,
        uint4* __restrict__ ctab) {
    int quad = blockIdx.x * 256 + threadIdx.x;
    if (quad >= NQUAD) return;
    #pragma unroll
    for (int q = 0; q < 2; q++) {
        float4 f = ((const float4*)lg)[(size_t)q * NQUAD + quad];
        float M = finv(mq[q]);
        uint4 cv;
        cv.x = ((unsigned)f2bf(f.x) << 16) | f2bf(__expf(f.x - M));
        cv.y = ((unsigned)f2bf(f.y) << 16) | f2bf(__expf(f.y - M));
        cv.z = ((unsigned)f2bf(f.z) << 16) | f2bf(__expf(f.z - M));
        cv.w = ((unsigned)f2bf(f.w) << 16) | f2bf(__expf(f.w - M));
        ctab[(size_t)q * NQUAD + quad] = cv;
    }
}

__global__ __launch_bounds__(64) void emain_kernel(
        const int* __restrict__ pass, const int* __restrict__ good,
        const int* __restrict__ qidx, const uint4* __restrict__ ctab,
        float4* __restrict__ acc) {
    int bid  = blockIdx.x;
    int c    = bid % NCHUNK;
    int rest = bid / NCHUNK;
    int par  = rest & 1;
    int grp  = rest >> 1;
    int lane = threadIdx.x;

    int t0 = par + 2 * (grp * GEV);
    int q  = qidx[t0] & 1;

    __shared__ uint4 ct[CHUNKQ];
    for (int i = lane; i < CHUNKQ; i += 64)
        ct[i] = ctab[(size_t)q * NQUAD + c * CHUNKQ + i];
    __syncthreads();

    int idx[SLOTS];
    #pragma unroll
    for (int s = 0; s < SLOTS; s++) {
        int i = s * 64 + lane;
        idx[s] = (i < CHUNKQ) ? i : (CHUNKQ - 1);
    }
    bool lastok = lane < LASTW;

    #pragma unroll
    for (int e = 0; e < GEV; e++) {
        int t = t0 + 2 * e;
        const int4* pbm = (const int4*)pass + (size_t)t * NQUAD + c * CHUNKQ;
        const int4* gbm = (const int4*)good + (size_t)t * NQUAD + c * CHUNKQ;

        int4 pm[SLOTS], gm[SLOTS];
        #pragma unroll
        for (int s = 0; s < SLOTS; s++) pm[s] = pbm[idx[s]];
        #pragma unroll
        for (int s = 0; s < SLOTS; s++) gm[s] = gbm[idx[s]];

        float sa = 0.f, sga = 0.f;
        int np = 0, ng = 0;
        #pragma unroll
        for (int s = 0; s < SLOTS; s++) {
            uint4 cv = ct[idx[s]];
            int4 p = pm[s], gmm = gm[s];
            if (s == SLOTS - 1 && !lastok) {
                p = make_int4(0, 0, 0, 0);
                gmm = make_int4(0, 0, 0, 0);
            }
            np += p.x + p.y + p.z + p.w;
            ng += gmm.x + gmm.y + gmm.z + gmm.w;
            sa  += p.x ? eLO(cv.x) : 0.0f;
            sa  += p.y ? eLO(cv.y) : 0.0f;
            sa  += p.z ? eLO(cv.z) : 0.0f;
            sa  += p.w ? eLO(cv.w) : 0.0f;
            sga += gmm.x ? lHI(cv.x) : 0.0f;
            sga += gmm.y ? lHI(cv.y) : 0.0f;
            sga += gmm.z ? lHI(cv.z) : 0.0f;
            sga += gmm.w ? lHI(cv.w) : 0.0f;
        }
        for (int off = 32; off; off >>= 1) {
            sa  += __shfl_xor(sa, off);
            sga += __shfl_xor(sga, off);
            np  += __shfl_xor(np, off);
            ng  += __shfl_xor(ng, off);
        }
        if (lane == 0)
            acc[(size_t)t * NCHUNK + c] = make_float4(sa, sga, (float)np, (float)ng);
    }
}

__global__ __launch_bounds__(1024) void final_kernel(
        const int* __restrict__ qidx, const float4* __restrict__ acc,
        const unsigned* __restrict__ mq, float* __restrict__ out) {
    int t = threadIdx.x;
    float s = 0.f, sg = 0.f, np = 0.f, ng = 0.f;
    int q = 0;
    if (t < T_SEL) {
        #pragma unroll 4
        for (int c = 0; c < NCHUNK; c++) {
            float4 a = acc[(size_t)t * NCHUNK + c];
            s += a.x; sg += a.y; np += a.z; ng += a.w;
        }
        q = qidx[t] & 1;
    }
    float M  = finv(mq[q]);
    float nb = np - ng;
    int valid = (t < T_SEL) && (ng > 0.5f) && (nb > 0.5f);

    __shared__ int sc[1024];
    sc[t] = valid;
    __syncthreads();
    for (int off = 1; off < 1024; off <<= 1) {
        int v = (t >= off) ? sc[t - off] : 0;
        __syncthreads();
        sc[t] += v;
        __syncthreads();
    }
    int sb    = sc[t] - valid;
    int steps = sc[1023];

    float ce   = logf(s) + M - sg / fmaxf(ng, 1.0f);
    float wgt  = powf(0.995f, (float)sb) * nb / fmaxf(np, 1.0f);
    float term = valid ? wgt * ce : 0.0f;

    __shared__ float sf[1024];
    sf[t] = term;
    __syncthreads();
    for (int off = 512; off; off >>= 1) {
        if (t < off) sf[t] += sf[t + off];
        __syncthreads();
    }
    if (t == 0) out[0] = sf[0] / fmaxf((float)steps, 1.0f);
}

extern "C" void kernel_launch(void* const* d_in, const int* in_sizes, int n_in,
                              void* d_out, int out_size, void* d_ws, size_t ws_size,
                              hipStream_t stream) {
    const float* X     = (const float*)d_in[0];
    const float* W1    = (const float*)d_in[1];
    const float* b1    = (const float*)d_in[2];
    const float* W2    = (const float*)d_in[3];
    const float* b2    = (const float*)d_in[4];
    const float* keysW = (const float*)d_in[5];
    const int*   pass  = (const int*)d_in[6];
    const int*   good  = (const int*)d_in[7];
    const int*   qidx  = (const int*)d_in[8];

    float*    ws = (float*)d_ws;
    float*    wk = ws + WK_OFF;
    float*    ck = ws + CK_OFF;
    unsigned* mq = (unsigned*)(ws + MQ_OFF);
    float*    P  = ws + P_OFF;
    float*    lg = ws + LG_OFF;
    float*    out = (float*)d_out;

    bool big = (ws_size >= WS_NEED);

    if (big) {
        unsigned long long* pb = (unsigned long long*)(ws + PB_OFF);
        unsigned long long* gb = (unsigned long long*)(ws + GB_OFF);
        unsigned* ptab = (unsigned*)(ws + PTAB_OFF);
        float4*   accb = (float4*)(ws + ACCB_OFF);

        hipLaunchKernelGGL(pack_kernel, dim3((T_SEL * WCH) / 4), dim3(256), 0, stream,
                           pass, good, pb, gb);
        hipLaunchKernelGGL(prep_kernel, dim3(1), dim3(256), 0, stream,
                           W2, b2, keysW, wk, ck, mq);
        hipLaunchKernelGGL(mlp_kernel, dim3(NBLK * JSPLIT), dim3(64), 0, stream,
                           X, W1, b1, wk, P);
        hipLaunchKernelGGL(logits_fin, dim3((N_CL + 255) / 256), dim3(256), 0, stream,
                           P, ck, lg, mq);
        hipLaunchKernelGGL(eperm_kernel, dim3((2 * BPR * 64 + 255) / 256), dim3(256), 0, stream,
                           lg, mq, (unsigned*)ptab);
        hipLaunchKernelGGL(ebit_kernel, dim3(NCH * 2 * GEB), dim3(256), 0, stream,
                           pb, gb, qidx, ptab, accb);
        hipLaunchKernelGGL(final2_kernel, dim3(1), dim3(1024), 0, stream,
                           qidx, accb, mq, out);
    } else {
        uint4*  ctab = (uint4*)(ws + CTAB_OFF);
        float4* acco = (float4*)(ws + ACCO_OFF);

        hipLaunchKernelGGL(prep_kernel, dim3(1), dim3(256), 0, stream,
                           W2, b2, keysW, wk, ck, mq);
        hipLaunchKernelGGL(mlp_kernel, dim3(NBLK * JSPLIT), dim3(64), 0, stream,
                           X, W1, b1, wk, P);
        hipLaunchKernelGGL(logits_fin, dim3((N_CL + 255) / 256), dim3(256), 0, stream,
                           P, ck, lg, mq);
        hipLaunchKernelGGL(epack_kernel, dim3((NQUAD + 255) / 256), dim3(256), 0, stream,
                           lg, mq, ctab);
        hipLaunchKernelGGL(emain_kernel, dim3(NCHUNK * 200), dim3(64), 0, stream,
                           pass, good, qidx, ctab, acco);
        hipLaunchKernelGGL(final_kernel, dim3(1), dim3(1024), 0, stream,
                           qidx, acco, mq, out);
    }
}

// Round 10
// 145.427 us; speedup vs baseline: 1.6971x; 1.6971x over previous
//
#include <hip/hip_runtime.h>
#include <hip/hip_bf16.h>

#define N_CL   50000
#define FEAT   64
#define HID    256
#define KD     256
#define T_SEL  1000
#define NBLK   782                 // ceil(50000/64) clause groups
#define JSPLIT 4                   // hidden-quarter blocks per clause group (R4-proven)
#define DCHUNK 10                  // blocks per event in the event phase (R2-proven)

// ws layout (in floats)
#define WK_OFF  0                          // 256*2 folded weights
#define CK_OFF  512                        // 2 bias constants
#define MQ_OFF  514                        // 2 uint max-keys
#define P_OFF   520                        // JSPLIT*2*N_CL partial logits
#define LG_OFF  (P_OFF + JSPLIT * 2 * N_CL)   // 2*N_CL final logits
#define ACC_OFF (LG_OFF + 2 * N_CL)        // T_SEL*4 accumulators (s, sg, np, ng)

__device__ __forceinline__ unsigned fkey(float f) {
    unsigned u = __float_as_uint(f);
    return (u & 0x80000000u) ? ~u : (u | 0x80000000u);   // monotone float->uint
}
__device__ __forceinline__ float finv(unsigned k) {
    unsigned u = (k & 0x80000000u) ? (k ^ 0x80000000u) : ~k;
    return __uint_as_float(u);
}

// ---------------------------------------------------------------- kernel A
// Wk[j][q] = dot(W2 row j, keys_W row q); ck[q] = dot(keys_W[q], b2).
// Also zeroes the per-event accumulators and max keys (needed every call:
// event_kernel accumulates via atomicAdd).
__global__ __launch_bounds__(256) void prep_kernel(
        const float* __restrict__ W2, const float* __restrict__ b2,
        const float* __restrict__ keysW,
        float* __restrict__ wk, float* __restrict__ ck,
        unsigned* __restrict__ mq, float* __restrict__ acc) {
    __shared__ float sk0[KD], sk1[KD], sb2[KD], red[256];
    int tid = threadIdx.x;
    sk0[tid] = keysW[tid];
    sk1[tid] = keysW[KD + tid];
    sb2[tid] = b2[tid];
    for (int i = tid; i < T_SEL * 4; i += 256) acc[i] = 0.0f;
    if (tid < 2) mq[tid] = 0u;
    __syncthreads();

    const float* w2r = W2 + (size_t)tid * KD;
    float a0 = 0.f, a1 = 0.f;
    #pragma unroll 4
    for (int k = 0; k < KD; k++) {
        float w = w2r[k];
        a0 = fmaf(w, sk0[k], a0);
        a1 = fmaf(w, sk1[k], a1);
    }
    wk[tid * 2 + 0] = a0;
    wk[tid * 2 + 1] = a1;

    red[tid] = sk0[tid] * sb2[tid];
    __syncthreads();
    for (int s = 128; s > 0; s >>= 1) { if (tid < s) red[tid] += red[tid + s]; __syncthreads(); }
    if (tid == 0) ck[0] = red[0];
    __syncthreads();
    red[tid] = sk1[tid] * sb2[tid];
    __syncthreads();
    for (int s = 128; s > 0; s >>= 1) { if (tid < s) red[tid] += red[tid + s]; __syncthreads(); }
    if (tid == 0) ck[1] = red[0];
}

// ---------------------------------------------------------------- kernel B
// MLP partial logits (R4-proven, ~11us). k-loop FULLY unrolled so x[] is
// compile-time indexed -> stays in VGPRs (partial unroll => scratch spill).
// W1/b1/wk addresses are wave-uniform -> scalar loads.
__global__ __launch_bounds__(64, 2) void mlp_kernel(
        const float* __restrict__ X, const float* __restrict__ W1,
        const float* __restrict__ b1, const float* __restrict__ wk,
        float* __restrict__ P) {
    int nb = blockIdx.x >> 2;       // p adjacent: 4 blocks sharing X rows
    int p  = blockIdx.x & 3;        // dispatch together -> X L2/L3-hot
    int n  = nb * 64 + threadIdx.x;
    int nc = (n < N_CL) ? n : (N_CL - 1);

    float x[FEAT];
    const float4* xp = (const float4*)(X + (size_t)nc * FEAT);
    #pragma unroll
    for (int k4 = 0; k4 < FEAT / 4; k4++) {
        float4 v = xp[k4];
        x[4 * k4 + 0] = v.x; x[4 * k4 + 1] = v.y;
        x[4 * k4 + 2] = v.z; x[4 * k4 + 3] = v.w;
    }

    float l0 = 0.f, l1 = 0.f;
    int j0 = p * 64;
    for (int jg = 0; jg < 64; jg += 16) {   // runtime loop: h indexed by u only
        float h[16];
        #pragma unroll
        for (int u = 0; u < 16; u++) h[u] = b1[j0 + jg + u];
        #pragma unroll
        for (int k = 0; k < FEAT; k++) {    // FULL unroll: x[k] static
            const float* w1r = W1 + (size_t)k * HID + j0 + jg;
            float xv = x[k];
            #pragma unroll
            for (int u = 0; u < 16; u++) h[u] = fmaf(xv, w1r[u], h[u]);
        }
        #pragma unroll
        for (int u = 0; u < 16; u++) {
            float hv = fmaxf(h[u], 0.0f);
            l0 = fmaf(hv, wk[(j0 + jg + u) * 2 + 0], l0);
            l1 = fmaf(hv, wk[(j0 + jg + u) * 2 + 1], l1);
        }
    }
    if (n < N_CL) {
        P[((size_t)p * 2 + 0) * N_CL + n] = l0;
        P[((size_t)p * 2 + 1) * N_CL + n] = l1;
    }
}

// ---------------------------------------------------------------- kernel C
// Sum the JSPLIT partials, add ck, write final logits, atomicMax row maxes.
__global__ __launch_bounds__(256) void logits_fin(
        const float* __restrict__ P, const float* __restrict__ ck,
        float* __restrict__ lg, unsigned* __restrict__ mq) {
    int n = blockIdx.x * 256 + threadIdx.x;
    float m0 = -1e30f, m1 = -1e30f;
    if (n < N_CL) {
        float l0 = ck[0], l1 = ck[1];
        #pragma unroll
        for (int p = 0; p < JSPLIT; p++) {
            l0 += P[((size_t)p * 2 + 0) * N_CL + n];
            l1 += P[((size_t)p * 2 + 1) * N_CL + n];
        }
        lg[n]        = l0;
        lg[N_CL + n] = l1;
        m0 = l0; m1 = l1;
    }
    for (int off = 32; off; off >>= 1) {
        m0 = fmaxf(m0, __shfl_xor(m0, off));
        m1 = fmaxf(m1, __shfl_xor(m1, off));
    }
    __shared__ float sm0[4], sm1[4];
    int w = threadIdx.x >> 6;
    if ((threadIdx.x & 63) == 0) { sm0[w] = m0; sm1[w] = m1; }
    __syncthreads();
    if (threadIdx.x == 0) {
        m0 = fmaxf(fmaxf(sm0[0], sm0[1]), fmaxf(sm0[2], sm0[3]));
        m1 = fmaxf(fmaxf(sm1[0], sm1[1]), fmaxf(sm1[2], sm1[3]));
        atomicMax(mq + 0, fkey(m0));
        atomicMax(mq + 1, fkey(m1));
    }
}

// ---------------------------------------------------------------- kernel D
// Event phase (R2-proven, 115.5us measured = pure-read pace of its own
// 400MB mask input; pack_kernel doing NOTHING but reading the same bytes
// took 120us). Streaming pass over the int32 masks: per event accumulate
// s = sum_passive exp(l - M), sg = sum_good l, np, ng. Exact f32 math.
#define EBODY(pp, gg, ll)                                   \
    do {                                                    \
        np += pp.x + pp.y + pp.z + pp.w;                    \
        ng += gg.x + gg.y + gg.z + gg.w;                    \
        float e0 = __expf(ll.x - M), e1 = __expf(ll.y - M); \
        float e2 = __expf(ll.z - M), e3 = __expf(ll.w - M); \
        s  = fmaf((float)pp.x, e0, s);                      \
        s  = fmaf((float)pp.y, e1, s);                      \
        s  = fmaf((float)pp.z, e2, s);                      \
        s  = fmaf((float)pp.w, e3, s);                      \
        sg = fmaf((float)gg.x, ll.x, sg);                   \
        sg = fmaf((float)gg.y, ll.y, sg);                   \
        sg = fmaf((float)gg.z, ll.z, sg);                   \
        sg = fmaf((float)gg.w, ll.w, sg);                   \
    } while (0)

__global__ __launch_bounds__(256) void event_kernel(
        const int* __restrict__ pass, const int* __restrict__ good,
        const int* __restrict__ qidx, const float* __restrict__ lg,
        const unsigned* __restrict__ mq, float* __restrict__ acc) {
    int t = blockIdx.x / DCHUNK;
    int c = blockIdx.x % DCHUNK;
    int q = qidx[t] & 1;
    float M = finv(mq[q]);
    const float4* lrow = (const float4*)(lg + (size_t)q * N_CL);
    const int4*   prow = (const int4*)(pass + (size_t)t * N_CL);
    const int4*   grow = (const int4*)(good + (size_t)t * N_CL);

    float s = 0.f, sg = 0.f;
    int np = 0, ng = 0;
    for (int i = c * 256 + (int)threadIdx.x; i < N_CL / 4; i += DCHUNK * 256) {
        int4   p = prow[i];
        int4   g = grow[i];
        float4 l = lrow[i];
        EBODY(p, g, l);
    }
    // wave reduce (64 lanes)
    for (int off = 32; off; off >>= 1) {
        s  += __shfl_xor(s, off);
        sg += __shfl_xor(sg, off);
        np += __shfl_xor(np, off);
        ng += __shfl_xor(ng, off);
    }
    __shared__ float rs[4], rsg[4];
    __shared__ int   rnp[4], rng[4];
    int w = threadIdx.x >> 6;
    if ((threadIdx.x & 63) == 0) { rs[w] = s; rsg[w] = sg; rnp[w] = np; rng[w] = ng; }
    __syncthreads();
    if (threadIdx.x == 0) {
        s  = rs[0] + rs[1] + rs[2] + rs[3];
        sg = rsg[0] + rsg[1] + rsg[2] + rsg[3];
        np = rnp[0] + rnp[1] + rnp[2] + rnp[3];
        ng = rng[0] + rng[1] + rng[2] + rng[3];
        atomicAdd(&acc[t * 4 + 0], s);
        atomicAdd(&acc[t * 4 + 1], sg);
        atomicAdd(&acc[t * 4 + 2], (float)np);
        atomicAdd(&acc[t * 4 + 3], (float)ng);
    }
}

// ---------------------------------------------------------------- kernel E
// Scan valid flags, apply discount, reduce to the scalar loss.
__global__ __launch_bounds__(1024) void final_kernel(
        const int* __restrict__ qidx, const float* __restrict__ acc,
        const unsigned* __restrict__ mq, float* __restrict__ out) {
    int t = threadIdx.x;
    float s = 0.f, sg = 0.f, np = 0.f, ng = 0.f;
    int q = 0;
    if (t < T_SEL) {
        const float* a = acc + t * 4;
        s = a[0]; sg = a[1]; np = a[2]; ng = a[3];
        q = qidx[t] & 1;
    }
    float M  = finv(mq[q]);
    float nb = np - ng;
    int valid = (t < T_SEL) && (ng > 0.5f) && (nb > 0.5f);

    __shared__ int sc[1024];
    sc[t] = valid;
    __syncthreads();
    for (int off = 1; off < 1024; off <<= 1) {
        int v = (t >= off) ? sc[t - off] : 0;
        __syncthreads();
        sc[t] += v;
        __syncthreads();
    }
    int sb    = sc[t] - valid;          // exclusive scan
    int steps = sc[1023];               // total valid count

    float ce   = logf(s) + M - sg / fmaxf(ng, 1.0f);
    float wgt  = powf(0.995f, (float)sb) * nb / fmaxf(np, 1.0f);
    float term = valid ? wgt * ce : 0.0f;

    __shared__ float sf[1024];
    sf[t] = term;
    __syncthreads();
    for (int off = 512; off; off >>= 1) {
        if (t < off) sf[t] += sf[t + off];
        __syncthreads();
    }
    if (t == 0) out[0] = sf[0] / fmaxf((float)steps, 1.0f);
}

extern "C" void kernel_launch(void* const* d_in, const int* in_sizes, int n_in,
                              void* d_out, int out_size, void* d_ws, size_t ws_size,
                              hipStream_t stream) {
    const float* X     = (const float*)d_in[0];
    const float* W1    = (const float*)d_in[1];
    const float* b1    = (const float*)d_in[2];
    const float* W2    = (const float*)d_in[3];
    const float* b2    = (const float*)d_in[4];
    const float* keysW = (const float*)d_in[5];
    const int*   pass  = (const int*)d_in[6];   // bool -> int32, one per clause
    const int*   good  = (const int*)d_in[7];
    const int*   qidx  = (const int*)d_in[8];

    float*    ws  = (float*)d_ws;
    float*    wk  = ws + WK_OFF;
    float*    ck  = ws + CK_OFF;
    unsigned* mq  = (unsigned*)(ws + MQ_OFF);
    float*    P   = ws + P_OFF;
    float*    lg  = ws + LG_OFF;
    float*    acc = ws + ACC_OFF;
    float*    out = (float*)d_out;

    hipLaunchKernelGGL(prep_kernel, dim3(1), dim3(256), 0, stream,
                       W2, b2, keysW, wk, ck, mq, acc);
    hipLaunchKernelGGL(mlp_kernel, dim3(NBLK * JSPLIT), dim3(64), 0, stream,
                       X, W1, b1, wk, P);
    hipLaunchKernelGGL(logits_fin, dim3((N_CL + 255) / 256), dim3(256), 0, stream,
                       P, ck, lg, mq);
    hipLaunchKernelGGL(event_kernel, dim3(T_SEL * DCHUNK), dim3(256), 0, stream,
                       pass, good, qidx, lg, mq, acc);
    hipLaunchKernelGGL(final_kernel, dim3(1), dim3(1024), 0, stream,
                       qidx, acc, mq, out);
}